// Round 5
// baseline (426.640 us; speedup 1.0000x reference)
//
#include <hip/hip_runtime.h>

#define N_NODES 100000
#define E_EDGES 1600000
#define E_TOT   1700000   // edges + self loops
#define FDIM    128       // F_IN and HEADS*HID
#define C2      10        // classes
#define YPAD    16        // yl/yr row stride (one 64B line)
#define NEG     0.2f
#define LOG2E   1.44269504088896f
#define PCLAMP  80.0f

#define NDEG    ((E_TOT + 255) / 256)        // 6641 edge chunks
#define NWT     128                          // 32768 / 256
#define GB1     ((N_NODES + 63) / 64)        // 1563 gemm1 blocks

typedef __attribute__((ext_vector_type(8))) short short8;
typedef __attribute__((ext_vector_type(4))) float f32x4;
typedef __attribute__((ext_vector_type(2))) float f32x2;

// 16-lane / 8-lane row reductions via DPP (pure VALU, no LDS pipe)
template <int CTRL>
__device__ __forceinline__ float dpp_add(float x) {
  return x + __int_as_float(
      __builtin_amdgcn_update_dpp(0, __float_as_int(x), CTRL, 0xF, 0xF, true));
}
__device__ __forceinline__ float row16_sum(float p) {
  p = dpp_add<0xB1>(p);
  p = dpp_add<0x4E>(p);
  p = dpp_add<0x141>(p);
  p = dpp_add<0x140>(p);
  return p;
}
__device__ __forceinline__ float row8_sum(float p) {
  p = dpp_add<0xB1>(p);    // xor 1
  p = dpp_add<0x4E>(p);    // xor 2
  p = dpp_add<0x141>(p);   // half-row mirror folds the two 4-quads of each 8-group
  return p;
}

// fp32 -> bf16 (round-nearest-even), and packed bf16x2 -> float2
__device__ __forceinline__ unsigned short f2bf(float f) {
  unsigned int u = __float_as_uint(f);
  u += 0x7FFFu + ((u >> 16) & 1u);
  return (unsigned short)(u >> 16);
}
__device__ __forceinline__ f32x2 up2v(unsigned int v) {
  f32x2 r;
  r.x = __uint_as_float(v << 16);
  r.y = __uint_as_float(v & 0xFFFF0000u);
  return r;
}

// ---------------- W1 transpose only (small, unblocks the fused gemm+count kernel) ----------------
__global__ __launch_bounds__(256) void k_prep_w(const float* __restrict__ W1l, const float* __restrict__ W1r,
                                                unsigned short* __restrict__ Wt) {
  int i = blockIdx.x * 256 + threadIdx.x;
  int n = i & 255, k = i >> 8;
  float v = (n < 128) ? W1l[k * 128 + n] : W1r[k * 128 + (n - 128)];
  Wt[n * 128 + k] = f2bf(v);   // B^T layout: row n, contiguous k
}

// ---------------- fused: Layer-1 GEMM (blocks < GB1) + degree count (rest) ----------------
__global__ __launch_bounds__(256) void k_gc(const float* __restrict__ x,
                                            const unsigned short* __restrict__ Wt,
                                            unsigned short* __restrict__ Hlb,
                                            unsigned short* __restrict__ Hrb,
                                            const int* __restrict__ ei, int* __restrict__ cnt,
                                            int* __restrict__ epos) {
  int b = blockIdx.x;
  if (b >= GB1) {
    int tid = (b - GB1) * 256 + threadIdx.x;
    if (tid < E_TOT) {
      int d = (tid < E_EDGES) ? ei[E_EDGES + tid] : (tid - E_EDGES);
      epos[tid] = atomicAdd(&cnt[d], 1);
    }
    return;
  }
  int w = threadIdx.x >> 6, lane = threadIdx.x & 63;
  int m = lane & 15, quad = lane >> 4;
  int row0 = b * 64 + w * 16;
  int arow = row0 + m;
  short8 A[4];
  bool aok = arow < N_NODES;
  const float4* ap = (const float4*)(x + (size_t)arow * FDIM + quad * 8);
#pragma unroll
  for (int c = 0; c < 4; c++) {
    short8 a = {};
    if (aok) {
      float4 v0 = ap[c * 8 + 0];
      float4 v1 = ap[c * 8 + 1];
      a[0] = (short)f2bf(v0.x); a[1] = (short)f2bf(v0.y);
      a[2] = (short)f2bf(v0.z); a[3] = (short)f2bf(v0.w);
      a[4] = (short)f2bf(v1.x); a[5] = (short)f2bf(v1.y);
      a[6] = (short)f2bf(v1.z); a[7] = (short)f2bf(v1.w);
    }
    A[c] = a;
  }

  int orow = row0 + quad * 4;
#pragma unroll
  for (int t0 = 0; t0 < 16; t0++) {
    const short8* bp = (const short8*)(Wt + (size_t)(t0 * 16 + m) * 128 + quad * 8);
    f32x4 acc = {0.f, 0.f, 0.f, 0.f};
#pragma unroll
    for (int c = 0; c < 4; c++)
      acc = __builtin_amdgcn_mfma_f32_16x16x32_bf16(A[c], bp[c * 4], acc, 0, 0, 0);
    int n0 = t0 * 16;
    unsigned short* dst = (n0 < 128) ? Hlb : Hrb;
    int col = (n0 < 128) ? n0 + m : (n0 - 128) + m;
#pragma unroll
    for (int r = 0; r < 4; r++) {
      int row = orow + r;
      if (row < N_NODES) dst[(size_t)row * FDIM + col] = f2bf(acc[r]);
    }
  }
}

#define SCAN_ITEMS 8
#define SCAN_CHUNK 2048
#define SCAN_NBLK  ((N_NODES + SCAN_CHUNK - 1) / SCAN_CHUNK)   // 49

__global__ __launch_bounds__(256) void k_scan1(const int* __restrict__ cnt, int* __restrict__ bsum) {
  int b = blockIdx.x, t = threadIdx.x;
  int base = b * SCAN_CHUNK + t * SCAN_ITEMS;
  int s = 0;
#pragma unroll
  for (int i = 0; i < SCAN_ITEMS; i++) {
    int idx = base + i;
    if (idx < N_NODES) s += cnt[idx];
  }
  __shared__ int sd[256];
  sd[t] = s; __syncthreads();
  for (int o = 128; o > 0; o >>= 1) {
    if (t < o) sd[t] += sd[t + o];
    __syncthreads();
  }
  if (t == 0) bsum[b] = sd[0];
}

__global__ __launch_bounds__(64) void k_scan2(const int* __restrict__ bsum, int* __restrict__ boff) {
  int t = threadIdx.x;
  int v = (t < SCAN_NBLK) ? bsum[t] : 0;
  int orig = v;
  for (int o = 1; o < 64; o <<= 1) {
    int u = __shfl_up(v, o);
    if (t >= o) v += u;
  }
  if (t < SCAN_NBLK) boff[t] = v - orig;
}

__global__ __launch_bounds__(256) void k_scan3(const int* __restrict__ cnt, const int* __restrict__ boff,
                                               int* __restrict__ row_ptr) {
  int b = blockIdx.x, t = threadIdx.x;
  int base = b * SCAN_CHUNK + t * SCAN_ITEMS;
  int vals[SCAN_ITEMS]; int ts = 0;
#pragma unroll
  for (int i = 0; i < SCAN_ITEMS; i++) {
    int idx = base + i;
    vals[i] = (idx < N_NODES) ? cnt[idx] : 0;
    ts += vals[i];
  }
  __shared__ int sd[256];
  sd[t] = ts; __syncthreads();
  for (int o = 1; o < 256; o <<= 1) {
    int v = 0;
    if (t >= o) v = sd[t - o];
    __syncthreads();
    sd[t] += v;
    __syncthreads();
  }
  int run = boff[b] + sd[t] - ts;
#pragma unroll
  for (int i = 0; i < SCAN_ITEMS; i++) {
    int idx = base + i;
    if (idx < N_NODES) row_ptr[idx] = run;
    run += vals[i];
  }
  if (b == 0 && t == 0) row_ptr[N_NODES] = E_TOT;
}

__global__ __launch_bounds__(256) void k_scatter(const int* __restrict__ ei,
                                                 const int* __restrict__ row_ptr,
                                                 const int* __restrict__ epos,
                                                 int* __restrict__ colA) {
  int tid = blockIdx.x * 256 + threadIdx.x;
  if (tid >= E_TOT) return;
  int s, d;
  if (tid < E_EDGES) { s = ei[tid]; d = ei[E_EDGES + tid]; }
  else { s = tid - E_EDGES; d = s; }
  colA[row_ptr[d] + epos[tid]] = s;
}

// ---------------- Layer-1 aggregation + in-wave CSR sort + fused layer-2 transform ----------------
// Issue-bound regime (r4: VALUBusy 95%): 2 edges/wave-iteration (lanes 0..31 = edge A,
// 32..63 = edge B), 4 ch/lane packed-f32, 8-lane DPP head reduce, LDS-staged W2 epilogue.
__global__ __launch_bounds__(256) void k_agg1(const unsigned short* __restrict__ Hlb,
                                              const unsigned short* __restrict__ Hrb,
                                              const int* __restrict__ row_ptr, int* __restrict__ colA,
                                              const float* __restrict__ att, const float* __restrict__ bias,
                                              const float* __restrict__ W2l, const float* __restrict__ W2r,
                                              float* __restrict__ yl, float* __restrict__ yr) {
  __shared__ float hsh[4][FDIM];
  __shared__ int sidx[4][64];
  __shared__ float w2t[2][C2][132];   // transposed W2, +4 pad
  // cooperative transpose-stage of W2l/W2r (grid exactly 25000*4 nodes: no early return)
  for (int i = threadIdx.x; i < FDIM * C2; i += 256) {
    int k = i / C2, cc = i - C2 * k;
    w2t[0][cc][k] = W2l[i];
    w2t[1][cc][k] = W2r[i];
  }
  __syncthreads();

  int w = threadIdx.x >> 6;
  int node = blockIdx.x * 4 + w;
  int lane = threadIdx.x & 63;
  int h  = lane >> 5;      // which edge of the pair this half-wave handles
  int cl = lane & 31;      // channel-lane: channels 4*cl .. 4*cl+3 (head = cl>>3)

  const uint2* Hl2 = (const uint2*)Hlb;   // row = 32 uint2 (256 B)
  const uint2* Hr2 = (const uint2*)Hrb;
  uint2 qr = Hr2[((size_t)node << 5) + cl];
  f32x2 xr01 = up2v(qr.x), xr23 = up2v(qr.y);
  float4 avv = ((const float4*)att)[cl];
  f32x2 a01; a01.x = avv.x * LOG2E; a01.y = avv.y * LOG2E;
  f32x2 a23; a23.x = avv.z * LOG2E; a23.y = avv.w * LOG2E;

  int beg = row_ptr[node], end = row_ptr[node + 1];
  int deg = end - beg;
  bool small = deg <= 64;

  if (small) {
    // in-wave bitonic sort (canonical ascending order -> deterministic FP order)
    int v = (lane < deg) ? colA[beg + lane] : 0x7FFFFFFF;
#pragma unroll
    for (int k = 2; k <= 64; k <<= 1) {
#pragma unroll
      for (int j = k >> 1; j > 0; j >>= 1) {
        int other = __shfl_xor(v, j);
        bool up = ((lane & k) == 0);
        bool lower = ((lane & j) == 0);
        int mn = min(v, other), mx = max(v, other);
        v = (lower == up) ? mn : mx;
      }
    }
    sidx[w][lane] = v;                      // intra-wave: DS ops in order
    if (lane < deg) colA[beg + lane] = v;   // sorted row for agg2
  } else {
    if (lane == 0) {
      for (int i = beg + 1; i < end; i++) {
        int vv = colA[i];
        int j = i - 1;
        while (j >= beg && colA[j] > vv) { colA[j + 1] = colA[j]; j--; }
        colA[j + 1] = vv;
      }
    }
    __threadfence_block();
  }

  float l = 0.f;
  f32x2 acc01 = {0.f, 0.f}, acc23 = {0.f, 0.f};

  auto comp = [&](uint2 qq, bool valid) {
    f32x2 xl01 = up2v(qq.x), xl23 = up2v(qq.y);
    f32x2 t01 = xl01 + xr01, t23 = xl23 + xr23;      // v_pk_add_f32
    f32x2 u01 = t01 * NEG,  u23 = t23 * NEG;         // v_pk_mul_f32
    t01.x = fmaxf(t01.x, u01.x); t01.y = fmaxf(t01.y, u01.y);   // leaky = max(t, 0.2t)
    t23.x = fmaxf(t23.x, u23.x); t23.y = fmaxf(t23.y, u23.y);
    f32x2 m = t01 * a01 + t23 * a23;                 // pk_mul + pk_fma
    float p = row8_sum(m.x + m.y);                   // per-head score (8 lanes = 32 ch)
    float ww = valid ? __builtin_amdgcn_exp2f(fminf(p, PCLAMP)) : 0.f;
    l += ww;
    acc01 += xl01 * ww;                              // pk_fma
    acc23 += xl23 * ww;
  };

  int full = deg >> 1;   // complete edge pairs
  if (small) {
    const int* si = sidx[w];
    int j = 0;
    for (; j + 4 <= full; j += 4) {                  // batch 4 pairs (8 edges)
      int s0 = si[2 * j + 0 + h], s1 = si[2 * j + 2 + h];
      int s2 = si[2 * j + 4 + h], s3 = si[2 * j + 6 + h];
      uint2 q0 = Hl2[((size_t)s0 << 5) + cl];
      uint2 q1 = Hl2[((size_t)s1 << 5) + cl];
      uint2 q2 = Hl2[((size_t)s2 << 5) + cl];
      uint2 q3 = Hl2[((size_t)s3 << 5) + cl];
      comp(q0, true); comp(q1, true); comp(q2, true); comp(q3, true);
    }
    for (; j < full; j++) {
      uint2 q0 = Hl2[((size_t)si[2 * j + h] << 5) + cl];
      comp(q0, true);
    }
    if (deg & 1) {                                   // odd tail: half 1 contributes exactly 0
      uint2 q0 = Hl2[((size_t)si[deg - 1] << 5) + cl];
      comp(q0, h == 0);
    }
  } else {
    const int* ca = colA + beg;
    int j = 0;
    for (; j + 4 <= full; j += 4) {
      int s0 = ca[2 * j + 0 + h], s1 = ca[2 * j + 2 + h];
      int s2 = ca[2 * j + 4 + h], s3 = ca[2 * j + 6 + h];
      uint2 q0 = Hl2[((size_t)s0 << 5) + cl];
      uint2 q1 = Hl2[((size_t)s1 << 5) + cl];
      uint2 q2 = Hl2[((size_t)s2 << 5) + cl];
      uint2 q3 = Hl2[((size_t)s3 << 5) + cl];
      comp(q0, true); comp(q1, true); comp(q2, true); comp(q3, true);
    }
    for (; j < full; j++) {
      uint2 q0 = Hl2[((size_t)ca[2 * j + h] << 5) + cl];
      comp(q0, true);
    }
    if (deg & 1) {
      uint2 q0 = Hl2[((size_t)ca[deg - 1] << 5) + cl];
      comp(q0, h == 0);
    }
  }

  // combine the two half-wave edge subsets (fixed tree -> deterministic)
  l       += __shfl_xor(l, 32);
  acc01.x += __shfl_xor(acc01.x, 32);
  acc01.y += __shfl_xor(acc01.y, 32);
  acc23.x += __shfl_xor(acc23.x, 32);
  acc23.y += __shfl_xor(acc23.y, 32);

  float inv = 1.f / l;
  if (lane < 32) {
    float4 bv = ((const float4*)bias)[cl];
    float4 o;
    o.x = fmaxf(fmaf(acc01.x, inv, bv.x), 0.f);     // fused ReLU
    o.y = fmaxf(fmaf(acc01.y, inv, bv.y), 0.f);
    o.z = fmaxf(fmaf(acc23.x, inv, bv.z), 0.f);
    o.w = fmaxf(fmaf(acc23.y, inv, bv.w), 0.f);
    ((float4*)hsh[w])[cl] = o;
  }
  if (lane < 2 * C2) {
    bool isl = lane < C2;
    int cc = isl ? lane : lane - C2;
    const float4* wrow = (const float4*)&w2t[isl ? 0 : 1][cc][0];
    float a2 = 0.f;
    const float4* h4 = (const float4*)hsh[w];
#pragma unroll
    for (int k4 = 0; k4 < 32; k4++) {
      float4 hv = h4[k4];    // broadcast (same addr across lanes)
      float4 wv = wrow[k4];  // per-lane row, padded stride
      a2 = fmaf(hv.x, wv.x, a2);
      a2 = fmaf(hv.y, wv.y, a2);
      a2 = fmaf(hv.z, wv.z, a2);
      a2 = fmaf(hv.w, wv.w, a2);
    }
    float* Y = isl ? yl : yr;
    Y[(size_t)node * YPAD + cc] = a2;
  }
}

// ---------------- Layer-2 aggregation: 1 wave/node, 4-way edge-parallel ----------------
__global__ __launch_bounds__(256) void k_agg2(const float* __restrict__ yl, const float* __restrict__ yr,
                                              const int* __restrict__ row_ptr, const int* __restrict__ colA,
                                              const float* __restrict__ att, const float* __restrict__ bias,
                                              float* __restrict__ outp) {
  int w = threadIdx.x >> 6;
  int node = blockIdx.x * 4 + w;
  if (node >= N_NODES) return;
  int lane = threadIdx.x & 63;
  int ch = lane & 15;
  int g  = lane >> 4;
  bool act = ch < C2;
  float xr = act ? yr[(size_t)node * YPAD + ch] : 0.f;
  float a  = act ? att[ch] * LOG2E : 0.f;
  int beg = row_ptr[node], end = row_ptr[node + 1];
  float l = 0.f, acc = 0.f;
  const float* ylL = yl + (act ? ch : 0);

  auto update = [&](float xl) {
    float t = xl + xr;
    t = t > 0.f ? t : NEG * t;
    float p = row16_sum(a * t);                 // 16-lane group reduce
    float wgt = __builtin_amdgcn_exp2f(fminf(p, PCLAMP));
    l += wgt;
    acc = fmaf(wgt, xl, acc);
  };

  int j = beg + g;
  for (; j + 4 < end; j += 8) {                 // 2 edges of this group: j, j+4
    int s0 = colA[j], s1 = colA[j + 4];
    float x0 = act ? ylL[(size_t)s0 << 4] : 0.f;
    float x1 = act ? ylL[(size_t)s1 << 4] : 0.f;
    update(x0); update(x1);
  }
  if (j < end) {
    int s0 = colA[j];
    float x0 = act ? ylL[(size_t)s0 << 4] : 0.f;
    update(x0);
  }

  // fixed combine tree across groups (deterministic): (g0+g1)+(g2+g3)
  l   += __shfl_xor(l, 16);
  acc += __shfl_xor(acc, 16);
  l   += __shfl_xor(l, 32);
  acc += __shfl_xor(acc, 32);
  if (g == 0 && act) outp[(size_t)node * C2 + ch] = acc / l + bias[ch];
}

extern "C" void kernel_launch(void* const* d_in, const int* in_sizes, int n_in,
                              void* d_out, int out_size, void* d_ws, size_t ws_size,
                              hipStream_t stream) {
  const float* x    = (const float*)d_in[0];
  const int*   ei   = (const int*)d_in[1];
  const float* W1l  = (const float*)d_in[2];
  const float* W1r  = (const float*)d_in[3];
  const float* att1 = (const float*)d_in[4];
  const float* b1   = (const float*)d_in[5];
  const float* W2l  = (const float*)d_in[6];
  const float* W2r  = (const float*)d_in[7];
  const float* att2 = (const float*)d_in[8];
  const float* b2   = (const float*)d_in[9];
  float* out = (float*)d_out;

  char* ws = (char*)d_ws;
  size_t off = 0;
  auto take = [&](size_t bytes) -> char* {
    char* p = ws + off;
    off = (off + bytes + 511) & ~(size_t)511;
    return p;
  };
  unsigned short* Hlb = (unsigned short*)take((size_t)N_NODES * FDIM * sizeof(unsigned short)); // 25.6 MB
  unsigned short* Hrb = (unsigned short*)take((size_t)N_NODES * FDIM * sizeof(unsigned short)); // 25.6 MB
  unsigned short* Wt  = (unsigned short*)take((size_t)256 * 128 * sizeof(unsigned short));      // 64 KB
  float* yl      = (float*)take((size_t)N_NODES * YPAD * sizeof(float));   // 6.4 MB
  float* yr      = (float*)take((size_t)N_NODES * YPAD * sizeof(float));   // 6.4 MB
  int*   cnt     = (int*)take((size_t)N_NODES * sizeof(int));
  int*   row_ptr = (int*)take((size_t)(N_NODES + 1) * sizeof(int));
  int*   colA    = (int*)take((size_t)E_TOT * sizeof(int));
  int*   epos    = (int*)take((size_t)E_TOT * sizeof(int));
  int*   bsum    = (int*)take(256);
  int*   boff    = (int*)take(256);
  if (off > ws_size) return;

  (void)hipMemsetAsync(cnt, 0, (size_t)N_NODES * sizeof(int), stream);
  k_prep_w <<<NWT, 256, 0, stream>>>(W1l, W1r, Wt);
  k_gc     <<<GB1 + NDEG, 256, 0, stream>>>(x, Wt, Hlb, Hrb, ei, cnt, epos);
  k_scan1  <<<SCAN_NBLK, 256, 0, stream>>>(cnt, bsum);
  k_scan2  <<<1, 64, 0, stream>>>(bsum, boff);
  k_scan3  <<<SCAN_NBLK, 256, 0, stream>>>(cnt, boff, row_ptr);
  k_scatter<<<(E_TOT + 255) / 256, 256, 0, stream>>>(ei, row_ptr, epos, colA);
  k_agg1   <<<(N_NODES + 3) / 4, 256, 0, stream>>>(Hlb, Hrb, row_ptr, colA, att1, b1, W2l, W2r, yl, yr);
  k_agg2   <<<(N_NODES + 3) / 4, 256, 0, stream>>>(yl, yr, row_ptr, colA, att2, b2, out);
}

// Round 6
// 403.972 us; speedup vs baseline: 1.0561x; 1.0561x over previous
//
#include <hip/hip_runtime.h>

#define N_NODES 100000
#define E_EDGES 1600000
#define E_TOT   1700000   // edges + self loops
#define FDIM    128       // F_IN and HEADS*HID
#define C2      10        // classes
#define YPAD    16        // yl/yr row stride (one 64B line)
#define NEG     0.2f
#define LOG2E   1.44269504088896f
#define PCLAMP  80.0f

#define NDEG    ((E_TOT + 255) / 256)        // 6641 edge chunks
#define NWT     128                          // 32768 / 256
#define GB1     ((N_NODES + 63) / 64)        // 1563 gemm1 blocks

typedef __attribute__((ext_vector_type(8))) short short8;
typedef __attribute__((ext_vector_type(4))) float f32x4;
typedef __attribute__((ext_vector_type(2))) float f32x2;

// 16-lane row reduction via DPP (pure VALU, no LDS pipe)
template <int CTRL>
__device__ __forceinline__ float dpp_add(float x) {
  return x + __int_as_float(
      __builtin_amdgcn_update_dpp(0, __float_as_int(x), CTRL, 0xF, 0xF, true));
}
__device__ __forceinline__ float row16_sum(float p) {
  p = dpp_add<0xB1>(p);
  p = dpp_add<0x4E>(p);
  p = dpp_add<0x141>(p);
  p = dpp_add<0x140>(p);
  return p;
}

// fp32 -> bf16 (round-nearest-even), and packed bf16x2 -> float2
__device__ __forceinline__ unsigned short f2bf(float f) {
  unsigned int u = __float_as_uint(f);
  u += 0x7FFFu + ((u >> 16) & 1u);
  return (unsigned short)(u >> 16);
}
__device__ __forceinline__ f32x2 up2v(unsigned int v) {
  f32x2 r;
  r.x = __uint_as_float(v << 16);
  r.y = __uint_as_float(v & 0xFFFF0000u);
  return r;
}

// ---------------- W1 transpose + cnt zeroing (replaces the hipMemsetAsync dispatch) ----------------
__global__ __launch_bounds__(256) void k_prep_w(const float* __restrict__ W1l, const float* __restrict__ W1r,
                                                unsigned short* __restrict__ Wt, int* __restrict__ cnt) {
  int i = blockIdx.x * 256 + threadIdx.x;
  int n = i & 255, k = i >> 8;
  float v = (n < 128) ? W1l[k * 128 + n] : W1r[k * 128 + (n - 128)];
  Wt[n * 128 + k] = f2bf(v);   // B^T layout: row n, contiguous k
  for (int c = i; c < N_NODES; c += NWT * 256) cnt[c] = 0;
}

// ---------------- fused: Layer-1 GEMM (blocks < GB1) + degree count (rest) ----------------
__global__ __launch_bounds__(256) void k_gc(const float* __restrict__ x,
                                            const unsigned short* __restrict__ Wt,
                                            unsigned short* __restrict__ Hlb,
                                            unsigned short* __restrict__ Hrb,
                                            const int* __restrict__ ei, int* __restrict__ cnt,
                                            int* __restrict__ epos) {
  int b = blockIdx.x;
  if (b >= GB1) {
    int tid = (b - GB1) * 256 + threadIdx.x;
    if (tid < E_TOT) {
      int d = (tid < E_EDGES) ? ei[E_EDGES + tid] : (tid - E_EDGES);
      epos[tid] = atomicAdd(&cnt[d], 1);
    }
    return;
  }
  int w = threadIdx.x >> 6, lane = threadIdx.x & 63;
  int m = lane & 15, quad = lane >> 4;
  int row0 = b * 64 + w * 16;
  int arow = row0 + m;
  short8 A[4];
  bool aok = arow < N_NODES;
  const float4* ap = (const float4*)(x + (size_t)arow * FDIM + quad * 8);
#pragma unroll
  for (int c = 0; c < 4; c++) {
    short8 a = {};
    if (aok) {
      float4 v0 = ap[c * 8 + 0];
      float4 v1 = ap[c * 8 + 1];
      a[0] = (short)f2bf(v0.x); a[1] = (short)f2bf(v0.y);
      a[2] = (short)f2bf(v0.z); a[3] = (short)f2bf(v0.w);
      a[4] = (short)f2bf(v1.x); a[5] = (short)f2bf(v1.y);
      a[6] = (short)f2bf(v1.z); a[7] = (short)f2bf(v1.w);
    }
    A[c] = a;
  }

  int orow = row0 + quad * 4;
#pragma unroll
  for (int t0 = 0; t0 < 16; t0++) {
    const short8* bp = (const short8*)(Wt + (size_t)(t0 * 16 + m) * 128 + quad * 8);
    f32x4 acc = {0.f, 0.f, 0.f, 0.f};
#pragma unroll
    for (int c = 0; c < 4; c++)
      acc = __builtin_amdgcn_mfma_f32_16x16x32_bf16(A[c], bp[c * 4], acc, 0, 0, 0);
    int n0 = t0 * 16;
    unsigned short* dst = (n0 < 128) ? Hlb : Hrb;
    int col = (n0 < 128) ? n0 + m : (n0 - 128) + m;
#pragma unroll
    for (int r = 0; r < 4; r++) {
      int row = orow + r;
      if (row < N_NODES) dst[(size_t)row * FDIM + col] = f2bf(acc[r]);
    }
  }
}

#define SCAN_ITEMS 8
#define SCAN_CHUNK 2048
#define SCAN_NBLK  ((N_NODES + SCAN_CHUNK - 1) / SCAN_CHUNK)   // 49

__global__ __launch_bounds__(256) void k_scan1(const int* __restrict__ cnt, int* __restrict__ bsum) {
  int b = blockIdx.x, t = threadIdx.x;
  int base = b * SCAN_CHUNK + t * SCAN_ITEMS;
  int s = 0;
#pragma unroll
  for (int i = 0; i < SCAN_ITEMS; i++) {
    int idx = base + i;
    if (idx < N_NODES) s += cnt[idx];
  }
  __shared__ int sd[256];
  sd[t] = s; __syncthreads();
  for (int o = 128; o > 0; o >>= 1) {
    if (t < o) sd[t] += sd[t + o];
    __syncthreads();
  }
  if (t == 0) bsum[b] = sd[0];
}

// scan3 with integrated block-offset computation (scan2 deleted): wave 0 sums bsum[0..b)
__global__ __launch_bounds__(256) void k_scan3(const int* __restrict__ cnt, const int* __restrict__ bsum,
                                               int* __restrict__ row_ptr) {
  __shared__ int boffs;
  int b = blockIdx.x, t = threadIdx.x;
  if (t < 64) {
    int v = (t < b) ? bsum[t] : 0;     // b <= 48 < 64: full prefix covered by one wave
    for (int o = 1; o < 64; o <<= 1) v += __shfl_xor(v, o);
    if (t == 0) boffs = v;
  }
  int base = b * SCAN_CHUNK + t * SCAN_ITEMS;
  int vals[SCAN_ITEMS]; int ts = 0;
#pragma unroll
  for (int i = 0; i < SCAN_ITEMS; i++) {
    int idx = base + i;
    vals[i] = (idx < N_NODES) ? cnt[idx] : 0;
    ts += vals[i];
  }
  __shared__ int sd[256];
  sd[t] = ts; __syncthreads();
  for (int o = 1; o < 256; o <<= 1) {
    int v = 0;
    if (t >= o) v = sd[t - o];
    __syncthreads();
    sd[t] += v;
    __syncthreads();
  }
  int run = boffs + sd[t] - ts;
#pragma unroll
  for (int i = 0; i < SCAN_ITEMS; i++) {
    int idx = base + i;
    if (idx < N_NODES) row_ptr[idx] = run;
    run += vals[i];
  }
  if (b == 0 && t == 0) row_ptr[N_NODES] = E_TOT;
}

__global__ __launch_bounds__(256) void k_scatter(const int* __restrict__ ei,
                                                 const int* __restrict__ row_ptr,
                                                 const int* __restrict__ epos,
                                                 int* __restrict__ colA) {
  int tid = blockIdx.x * 256 + threadIdx.x;
  if (tid >= E_TOT) return;
  int s, d;
  if (tid < E_EDGES) { s = ei[tid]; d = ei[E_EDGES + tid]; }
  else { s = tid - E_EDGES; d = s; }
  colA[row_ptr[d] + epos[tid]] = s;
}

// ---------------- Layer-1 aggregation + in-wave CSR sort + fused layer-2 transform ----------------
// Round-4 champion: 1 node/wave, 64-lane rows, 2 ch/lane packed-f32, batch-8 gathers,
// LDS-staged W2 epilogue. (Round-5's 2-edge restructure regressed: occupancy + latency cover.)
__global__ __launch_bounds__(256) void k_agg1(const unsigned short* __restrict__ Hlb,
                                              const unsigned short* __restrict__ Hrb,
                                              const int* __restrict__ row_ptr, int* __restrict__ colA,
                                              const float* __restrict__ att, const float* __restrict__ bias,
                                              const float* __restrict__ W2l, const float* __restrict__ W2r,
                                              float* __restrict__ yl, float* __restrict__ yr) {
  __shared__ float hsh[4][FDIM];
  __shared__ int sidx[4][64];
  __shared__ float w2t[2][C2][132];   // transposed W2, +4 pad -> near-conflict-free b128 reads
  // cooperative transpose-stage of W2l/W2r (grid is exactly 25000*4 nodes: no early return, barrier safe)
  for (int i = threadIdx.x; i < FDIM * C2; i += 256) {
    int k = i / C2, cc = i - C2 * k;
    w2t[0][cc][k] = W2l[i];
    w2t[1][cc][k] = W2r[i];
  }
  __syncthreads();

  int w = threadIdx.x >> 6;
  int node = blockIdx.x * 4 + w;
  int lane = threadIdx.x & 63;
  int c0 = 2 * lane;
  const unsigned int* Hl32 = (const unsigned int*)Hlb;   // row = 64 uints
  const unsigned int* Hr32 = (const unsigned int*)Hrb;
  f32x2 xr = up2v(Hr32[((size_t)node << 6) + lane]);
  f32x2 av; av.x = att[c0] * LOG2E; av.y = att[c0 + 1] * LOG2E;
  int beg = row_ptr[node], end = row_ptr[node + 1];
  int deg = end - beg;
  bool small = deg <= 64;

  if (small) {
    // in-wave bitonic sort (canonical ascending order -> deterministic FP order)
    int v = (lane < deg) ? colA[beg + lane] : 0x7FFFFFFF;
#pragma unroll
    for (int k = 2; k <= 64; k <<= 1) {
#pragma unroll
      for (int j = k >> 1; j > 0; j >>= 1) {
        int other = __shfl_xor(v, j);
        bool up = ((lane & k) == 0);
        bool lower = ((lane & j) == 0);
        int mn = min(v, other), mx = max(v, other);
        v = (lower == up) ? mn : mx;
      }
    }
    sidx[w][lane] = v;                      // intra-wave: DS ops in order
    if (lane < deg) colA[beg + lane] = v;   // sorted row for agg2
  } else {
    if (lane == 0) {
      for (int i = beg + 1; i < end; i++) {
        int vv = colA[i];
        int j = i - 1;
        while (j >= beg && colA[j] > vv) { colA[j + 1] = colA[j]; j--; }
        colA[j + 1] = vv;
      }
    }
    __threadfence_block();
  }

  float l = 0.f;
  f32x2 acc = {0.f, 0.f};
  auto update = [&](unsigned int vv) {
    f32x2 xl = up2v(vv);
    f32x2 t = xl + xr;                       // v_pk_add_f32
    f32x2 u = t * NEG;                       // v_pk_mul_f32
    t.x = fmaxf(t.x, u.x);                   // leaky = max(t, 0.2t)
    t.y = fmaxf(t.y, u.y);
    f32x2 m = t * av;                        // v_pk_mul_f32
    float p = row16_sum(m.x + m.y);
    float ww = __builtin_amdgcn_exp2f(fminf(p, PCLAMP));
    l += ww;
    acc += xl * ww;                          // v_pk_fma_f32
  };

  if (small) {
    const int* si = sidx[w];
    int j = 0;
    for (; j + 8 <= deg; j += 8) {
      unsigned int v0 = Hl32[((size_t)si[j + 0] << 6) + lane];
      unsigned int v1 = Hl32[((size_t)si[j + 1] << 6) + lane];
      unsigned int v2 = Hl32[((size_t)si[j + 2] << 6) + lane];
      unsigned int v3 = Hl32[((size_t)si[j + 3] << 6) + lane];
      unsigned int v4 = Hl32[((size_t)si[j + 4] << 6) + lane];
      unsigned int v5 = Hl32[((size_t)si[j + 5] << 6) + lane];
      unsigned int v6 = Hl32[((size_t)si[j + 6] << 6) + lane];
      unsigned int v7 = Hl32[((size_t)si[j + 7] << 6) + lane];
      update(v0); update(v1); update(v2); update(v3);
      update(v4); update(v5); update(v6); update(v7);
    }
    for (; j + 2 <= deg; j += 2) {
      unsigned int v0 = Hl32[((size_t)si[j + 0] << 6) + lane];
      unsigned int v1 = Hl32[((size_t)si[j + 1] << 6) + lane];
      update(v0); update(v1);
    }
    if (j < deg) update(Hl32[((size_t)si[j] << 6) + lane]);
  } else {
    for (int j = beg; j < end; j++) update(Hl32[((size_t)colA[j] << 6) + lane]);
  }

  float inv = 1.f / l;
  float ox = fmaxf(fmaf(acc.x, inv, bias[c0]),     0.f);   // fused ReLU
  float oy = fmaxf(fmaf(acc.y, inv, bias[c0 + 1]), 0.f);
  hsh[w][c0] = ox; hsh[w][c0 + 1] = oy;
  if (lane < 2 * C2) {
    bool isl = lane < C2;
    int cc = isl ? lane : lane - C2;
    const float4* wrow = (const float4*)&w2t[isl ? 0 : 1][cc][0];  // 528B row stride: 16B-aligned
    float a2 = 0.f;
    const float4* h4 = (const float4*)hsh[w];
#pragma unroll
    for (int k4 = 0; k4 < 32; k4++) {
      float4 hv = h4[k4];    // broadcast (same addr across lanes)
      float4 wv = wrow[k4];  // per-lane row, padded stride
      a2 = fmaf(hv.x, wv.x, a2);
      a2 = fmaf(hv.y, wv.y, a2);
      a2 = fmaf(hv.z, wv.z, a2);
      a2 = fmaf(hv.w, wv.w, a2);
    }
    float* Y = isl ? yl : yr;
    Y[(size_t)node * YPAD + cc] = a2;
  }
}

// ---------------- Layer-2 aggregation: 1 wave/node, 4-way edge-parallel, 4-deep ILP ----------------
__global__ __launch_bounds__(256) void k_agg2(const float* __restrict__ yl, const float* __restrict__ yr,
                                              const int* __restrict__ row_ptr, const int* __restrict__ colA,
                                              const float* __restrict__ att, const float* __restrict__ bias,
                                              float* __restrict__ outp) {
  int w = threadIdx.x >> 6;
  int node = blockIdx.x * 4 + w;
  if (node >= N_NODES) return;
  int lane = threadIdx.x & 63;
  int ch = lane & 15;
  int g  = lane >> 4;
  bool act = ch < C2;
  float xr = act ? yr[(size_t)node * YPAD + ch] : 0.f;
  float a  = act ? att[ch] * LOG2E : 0.f;
  int beg = row_ptr[node], end = row_ptr[node + 1];
  float l = 0.f, acc = 0.f;
  const float* ylL = yl + (act ? ch : 0);

  auto update = [&](float xl) {
    float t = xl + xr;
    t = t > 0.f ? t : NEG * t;
    float p = row16_sum(a * t);                 // 16-lane group reduce
    float wgt = __builtin_amdgcn_exp2f(fminf(p, PCLAMP));
    l += wgt;
    acc = fmaf(wgt, xl, acc);
  };

  int j = beg + g;
  for (; j + 12 < end; j += 16) {               // 4 edges of this group: j, j+4, j+8, j+12
    int s0 = colA[j], s1 = colA[j + 4], s2 = colA[j + 8], s3 = colA[j + 12];
    float x0 = act ? ylL[(size_t)s0 << 4] : 0.f;
    float x1 = act ? ylL[(size_t)s1 << 4] : 0.f;
    float x2 = act ? ylL[(size_t)s2 << 4] : 0.f;
    float x3 = act ? ylL[(size_t)s3 << 4] : 0.f;
    update(x0); update(x1); update(x2); update(x3);
  }
  for (; j + 4 < end; j += 8) {                 // 2 edges: j, j+4
    int s0 = colA[j], s1 = colA[j + 4];
    float x0 = act ? ylL[(size_t)s0 << 4] : 0.f;
    float x1 = act ? ylL[(size_t)s1 << 4] : 0.f;
    update(x0); update(x1);
  }
  if (j < end) {
    int s0 = colA[j];
    float x0 = act ? ylL[(size_t)s0 << 4] : 0.f;
    update(x0);
  }

  // fixed combine tree across groups (deterministic): (g0+g1)+(g2+g3)
  l   += __shfl_xor(l, 16);
  acc += __shfl_xor(acc, 16);
  l   += __shfl_xor(l, 32);
  acc += __shfl_xor(acc, 32);
  if (g == 0 && act) outp[(size_t)node * C2 + ch] = acc / l + bias[ch];
}

extern "C" void kernel_launch(void* const* d_in, const int* in_sizes, int n_in,
                              void* d_out, int out_size, void* d_ws, size_t ws_size,
                              hipStream_t stream) {
  const float* x    = (const float*)d_in[0];
  const int*   ei   = (const int*)d_in[1];
  const float* W1l  = (const float*)d_in[2];
  const float* W1r  = (const float*)d_in[3];
  const float* att1 = (const float*)d_in[4];
  const float* b1   = (const float*)d_in[5];
  const float* W2l  = (const float*)d_in[6];
  const float* W2r  = (const float*)d_in[7];
  const float* att2 = (const float*)d_in[8];
  const float* b2   = (const float*)d_in[9];
  float* out = (float*)d_out;

  char* ws = (char*)d_ws;
  size_t off = 0;
  auto take = [&](size_t bytes) -> char* {
    char* p = ws + off;
    off = (off + bytes + 511) & ~(size_t)511;
    return p;
  };
  unsigned short* Hlb = (unsigned short*)take((size_t)N_NODES * FDIM * sizeof(unsigned short)); // 25.6 MB
  unsigned short* Hrb = (unsigned short*)take((size_t)N_NODES * FDIM * sizeof(unsigned short)); // 25.6 MB
  unsigned short* Wt  = (unsigned short*)take((size_t)256 * 128 * sizeof(unsigned short));      // 64 KB
  float* yl      = (float*)take((size_t)N_NODES * YPAD * sizeof(float));   // 6.4 MB
  float* yr      = (float*)take((size_t)N_NODES * YPAD * sizeof(float));   // 6.4 MB
  int*   cnt     = (int*)take((size_t)N_NODES * sizeof(int));
  int*   row_ptr = (int*)take((size_t)(N_NODES + 1) * sizeof(int));
  int*   colA    = (int*)take((size_t)E_TOT * sizeof(int));
  int*   epos    = (int*)take((size_t)E_TOT * sizeof(int));
  int*   bsum    = (int*)take(256);
  if (off > ws_size) return;

  k_prep_w <<<NWT, 256, 0, stream>>>(W1l, W1r, Wt, cnt);
  k_gc     <<<GB1 + NDEG, 256, 0, stream>>>(x, Wt, Hlb, Hrb, ei, cnt, epos);
  k_scan1  <<<SCAN_NBLK, 256, 0, stream>>>(cnt, bsum);
  k_scan3  <<<SCAN_NBLK, 256, 0, stream>>>(cnt, bsum, row_ptr);
  k_scatter<<<(E_TOT + 255) / 256, 256, 0, stream>>>(ei, row_ptr, epos, colA);
  k_agg1   <<<(N_NODES + 3) / 4, 256, 0, stream>>>(Hlb, Hrb, row_ptr, colA, att1, b1, W2l, W2r, yl, yr);
  k_agg2   <<<(N_NODES + 3) / 4, 256, 0, stream>>>(yl, yr, row_ptr, colA, att2, b2, out);
}

// Round 7
// 402.715 us; speedup vs baseline: 1.0594x; 1.0031x over previous
//
#include <hip/hip_runtime.h>

#define N_NODES 100000
#define E_EDGES 1600000
#define E_TOT   1700000   // edges + self loops
#define FDIM    128       // F_IN and HEADS*HID
#define C2      10        // classes
#define YPAD    16        // yl/yr row stride (one 64B line)
#define NEG     0.2f
#define LOG2E   1.44269504088896f
#define PCLAMP  80.0f

#define NDEG    ((E_TOT + 255) / 256)        // 6641 edge chunks
#define NWT     128                          // 32768 / 256
#define GB1     ((N_NODES + 63) / 64)        // 1563 gemm1 blocks

typedef __attribute__((ext_vector_type(8))) short short8;
typedef __attribute__((ext_vector_type(4))) float f32x4;
typedef __attribute__((ext_vector_type(2))) float f32x2;

// 16-lane / 8-lane row reductions via DPP (pure VALU, no LDS pipe)
template <int CTRL>
__device__ __forceinline__ float dpp_add(float x) {
  return x + __int_as_float(
      __builtin_amdgcn_update_dpp(0, __float_as_int(x), CTRL, 0xF, 0xF, true));
}
__device__ __forceinline__ float row16_sum(float p) {
  p = dpp_add<0xB1>(p);
  p = dpp_add<0x4E>(p);
  p = dpp_add<0x141>(p);
  p = dpp_add<0x140>(p);
  return p;
}
__device__ __forceinline__ float row8_sum(float p) {
  p = dpp_add<0xB1>(p);    // xor 1 (quad_perm [1,0,3,2])
  p = dpp_add<0x4E>(p);    // xor 2 (quad_perm [2,3,0,1])
  p = dpp_add<0x141>(p);   // row_half_mirror: folds the two quads of each 8-lane group
  return p;
}

// fp32 -> bf16 (round-nearest-even), and packed bf16x2 -> float2
__device__ __forceinline__ unsigned short f2bf(float f) {
  unsigned int u = __float_as_uint(f);
  u += 0x7FFFu + ((u >> 16) & 1u);
  return (unsigned short)(u >> 16);
}
__device__ __forceinline__ f32x2 up2v(unsigned int v) {
  f32x2 r;
  r.x = __uint_as_float(v << 16);
  r.y = __uint_as_float(v & 0xFFFF0000u);
  return r;
}

// ---------------- W1 transpose + cnt zeroing (replaces the hipMemsetAsync dispatch) ----------------
__global__ __launch_bounds__(256) void k_prep_w(const float* __restrict__ W1l, const float* __restrict__ W1r,
                                                unsigned short* __restrict__ Wt, int* __restrict__ cnt) {
  int i = blockIdx.x * 256 + threadIdx.x;
  int n = i & 255, k = i >> 8;
  float v = (n < 128) ? W1l[k * 128 + n] : W1r[k * 128 + (n - 128)];
  Wt[n * 128 + k] = f2bf(v);   // B^T layout: row n, contiguous k
  for (int c = i; c < N_NODES; c += NWT * 256) cnt[c] = 0;
}

// ---------------- fused: Layer-1 GEMM (blocks < GB1) + degree count (rest) ----------------
__global__ __launch_bounds__(256) void k_gc(const float* __restrict__ x,
                                            const unsigned short* __restrict__ Wt,
                                            unsigned short* __restrict__ Hlb,
                                            unsigned short* __restrict__ Hrb,
                                            const int* __restrict__ ei, int* __restrict__ cnt,
                                            int* __restrict__ epos) {
  int b = blockIdx.x;
  if (b >= GB1) {
    int tid = (b - GB1) * 256 + threadIdx.x;
    if (tid < E_TOT) {
      int d = (tid < E_EDGES) ? ei[E_EDGES + tid] : (tid - E_EDGES);
      epos[tid] = atomicAdd(&cnt[d], 1);
    }
    return;
  }
  int w = threadIdx.x >> 6, lane = threadIdx.x & 63;
  int m = lane & 15, quad = lane >> 4;
  int row0 = b * 64 + w * 16;
  int arow = row0 + m;
  short8 A[4];
  bool aok = arow < N_NODES;
  const float4* ap = (const float4*)(x + (size_t)arow * FDIM + quad * 8);
#pragma unroll
  for (int c = 0; c < 4; c++) {
    short8 a = {};
    if (aok) {
      float4 v0 = ap[c * 8 + 0];
      float4 v1 = ap[c * 8 + 1];
      a[0] = (short)f2bf(v0.x); a[1] = (short)f2bf(v0.y);
      a[2] = (short)f2bf(v0.z); a[3] = (short)f2bf(v0.w);
      a[4] = (short)f2bf(v1.x); a[5] = (short)f2bf(v1.y);
      a[6] = (short)f2bf(v1.z); a[7] = (short)f2bf(v1.w);
    }
    A[c] = a;
  }

  int orow = row0 + quad * 4;
#pragma unroll
  for (int t0 = 0; t0 < 16; t0++) {
    const short8* bp = (const short8*)(Wt + (size_t)(t0 * 16 + m) * 128 + quad * 8);
    f32x4 acc = {0.f, 0.f, 0.f, 0.f};
#pragma unroll
    for (int c = 0; c < 4; c++)
      acc = __builtin_amdgcn_mfma_f32_16x16x32_bf16(A[c], bp[c * 4], acc, 0, 0, 0);
    int n0 = t0 * 16;
    unsigned short* dst = (n0 < 128) ? Hlb : Hrb;
    int col = (n0 < 128) ? n0 + m : (n0 - 128) + m;
#pragma unroll
    for (int r = 0; r < 4; r++) {
      int row = orow + r;
      if (row < N_NODES) dst[(size_t)row * FDIM + col] = f2bf(acc[r]);
    }
  }
}

#define SCAN_ITEMS 8
#define SCAN_CHUNK 2048
#define SCAN_NBLK  ((N_NODES + SCAN_CHUNK - 1) / SCAN_CHUNK)   // 49

__global__ __launch_bounds__(256) void k_scan1(const int* __restrict__ cnt, int* __restrict__ bsum) {
  int b = blockIdx.x, t = threadIdx.x;
  int base = b * SCAN_CHUNK + t * SCAN_ITEMS;
  int s = 0;
#pragma unroll
  for (int i = 0; i < SCAN_ITEMS; i++) {
    int idx = base + i;
    if (idx < N_NODES) s += cnt[idx];
  }
  __shared__ int sd[256];
  sd[t] = s; __syncthreads();
  for (int o = 128; o > 0; o >>= 1) {
    if (t < o) sd[t] += sd[t + o];
    __syncthreads();
  }
  if (t == 0) bsum[b] = sd[0];
}

// scan3 with integrated block-offset computation (scan2 deleted): wave 0 sums bsum[0..b)
__global__ __launch_bounds__(256) void k_scan3(const int* __restrict__ cnt, const int* __restrict__ bsum,
                                               int* __restrict__ row_ptr) {
  __shared__ int boffs;
  int b = blockIdx.x, t = threadIdx.x;
  if (t < 64) {
    int v = (t < b) ? bsum[t] : 0;     // b <= 48 < 64: full prefix covered by one wave
    for (int o = 1; o < 64; o <<= 1) v += __shfl_xor(v, o);
    if (t == 0) boffs = v;
  }
  int base = b * SCAN_CHUNK + t * SCAN_ITEMS;
  int vals[SCAN_ITEMS]; int ts = 0;
#pragma unroll
  for (int i = 0; i < SCAN_ITEMS; i++) {
    int idx = base + i;
    vals[i] = (idx < N_NODES) ? cnt[idx] : 0;
    ts += vals[i];
  }
  __shared__ int sd[256];
  sd[t] = ts; __syncthreads();
  for (int o = 1; o < 256; o <<= 1) {
    int v = 0;
    if (t >= o) v = sd[t - o];
    __syncthreads();
    sd[t] += v;
    __syncthreads();
  }
  int run = boffs + sd[t] - ts;
#pragma unroll
  for (int i = 0; i < SCAN_ITEMS; i++) {
    int idx = base + i;
    if (idx < N_NODES) row_ptr[idx] = run;
    run += vals[i];
  }
  if (b == 0 && t == 0) row_ptr[N_NODES] = E_TOT;
}

__global__ __launch_bounds__(256) void k_scatter(const int* __restrict__ ei,
                                                 const int* __restrict__ row_ptr,
                                                 const int* __restrict__ epos,
                                                 int* __restrict__ colA) {
  int tid = blockIdx.x * 256 + threadIdx.x;
  if (tid >= E_TOT) return;
  int s, d;
  if (tid < E_EDGES) { s = ei[tid]; d = ei[E_EDGES + tid]; }
  else { s = tid - E_EDGES; d = s; }
  colA[row_ptr[d] + epos[tid]] = s;
}

// ---------------- Layer-1 aggregation + in-wave CSR sort + fused layer-2 transform ----------------
// Champion structure: 1 node/wave, 64-lane rows, 2 ch/lane packed-f32, batch-8 gathers,
// LDS-staged W2 epilogue. This round: pk_max for leaky-ReLU.
__global__ __launch_bounds__(256) void k_agg1(const unsigned short* __restrict__ Hlb,
                                              const unsigned short* __restrict__ Hrb,
                                              const int* __restrict__ row_ptr, int* __restrict__ colA,
                                              const float* __restrict__ att, const float* __restrict__ bias,
                                              const float* __restrict__ W2l, const float* __restrict__ W2r,
                                              float* __restrict__ yl, float* __restrict__ yr) {
  __shared__ float hsh[4][FDIM];
  __shared__ int sidx[4][64];
  __shared__ float w2t[2][C2][132];   // transposed W2, +4 pad -> near-conflict-free b128 reads
  // cooperative transpose-stage of W2l/W2r (grid is exactly 25000*4 nodes: no early return, barrier safe)
  for (int i = threadIdx.x; i < FDIM * C2; i += 256) {
    int k = i / C2, cc = i - C2 * k;
    w2t[0][cc][k] = W2l[i];
    w2t[1][cc][k] = W2r[i];
  }
  __syncthreads();

  int w = threadIdx.x >> 6;
  int node = blockIdx.x * 4 + w;
  int lane = threadIdx.x & 63;
  int c0 = 2 * lane;
  const unsigned int* Hl32 = (const unsigned int*)Hlb;   // row = 64 uints
  const unsigned int* Hr32 = (const unsigned int*)Hrb;
  f32x2 xr = up2v(Hr32[((size_t)node << 6) + lane]);
  f32x2 av; av.x = att[c0] * LOG2E; av.y = att[c0 + 1] * LOG2E;
  int beg = row_ptr[node], end = row_ptr[node + 1];
  int deg = end - beg;
  bool small = deg <= 64;

  if (small) {
    // in-wave bitonic sort (canonical ascending order -> deterministic FP order)
    int v = (lane < deg) ? colA[beg + lane] : 0x7FFFFFFF;
#pragma unroll
    for (int k = 2; k <= 64; k <<= 1) {
#pragma unroll
      for (int j = k >> 1; j > 0; j >>= 1) {
        int other = __shfl_xor(v, j);
        bool up = ((lane & k) == 0);
        bool lower = ((lane & j) == 0);
        int mn = min(v, other), mx = max(v, other);
        v = (lower == up) ? mn : mx;
      }
    }
    sidx[w][lane] = v;                      // intra-wave: DS ops in order
    if (lane < deg) colA[beg + lane] = v;   // sorted row for agg2
  } else {
    if (lane == 0) {
      for (int i = beg + 1; i < end; i++) {
        int vv = colA[i];
        int j = i - 1;
        while (j >= beg && colA[j] > vv) { colA[j + 1] = colA[j]; j--; }
        colA[j + 1] = vv;
      }
    }
    __threadfence_block();
  }

  float l = 0.f;
  f32x2 acc = {0.f, 0.f};
  auto update = [&](unsigned int vv) {
    f32x2 xl = up2v(vv);
    f32x2 t = xl + xr;                       // v_pk_add_f32
    f32x2 u = t * NEG;                       // v_pk_mul_f32
    t = __builtin_elementwise_max(t, u);     // v_pk_max_f32: leaky = max(t, 0.2t)
    f32x2 m = t * av;                        // v_pk_mul_f32
    float p = row16_sum(m.x + m.y);
    float ww = __builtin_amdgcn_exp2f(fminf(p, PCLAMP));
    l += ww;
    acc += xl * ww;                          // v_pk_fma_f32
  };

  if (small) {
    const int* si = sidx[w];
    int j = 0;
    for (; j + 8 <= deg; j += 8) {
      unsigned int v0 = Hl32[((size_t)si[j + 0] << 6) + lane];
      unsigned int v1 = Hl32[((size_t)si[j + 1] << 6) + lane];
      unsigned int v2 = Hl32[((size_t)si[j + 2] << 6) + lane];
      unsigned int v3 = Hl32[((size_t)si[j + 3] << 6) + lane];
      unsigned int v4 = Hl32[((size_t)si[j + 4] << 6) + lane];
      unsigned int v5 = Hl32[((size_t)si[j + 5] << 6) + lane];
      unsigned int v6 = Hl32[((size_t)si[j + 6] << 6) + lane];
      unsigned int v7 = Hl32[((size_t)si[j + 7] << 6) + lane];
      update(v0); update(v1); update(v2); update(v3);
      update(v4); update(v5); update(v6); update(v7);
    }
    for (; j + 2 <= deg; j += 2) {
      unsigned int v0 = Hl32[((size_t)si[j + 0] << 6) + lane];
      unsigned int v1 = Hl32[((size_t)si[j + 1] << 6) + lane];
      update(v0); update(v1);
    }
    if (j < deg) update(Hl32[((size_t)si[j] << 6) + lane]);
  } else {
    for (int j = beg; j < end; j++) update(Hl32[((size_t)colA[j] << 6) + lane]);
  }

  float inv = 1.f / l;
  float ox = fmaxf(fmaf(acc.x, inv, bias[c0]),     0.f);   // fused ReLU
  float oy = fmaxf(fmaf(acc.y, inv, bias[c0 + 1]), 0.f);
  hsh[w][c0] = ox; hsh[w][c0 + 1] = oy;
  if (lane < 2 * C2) {
    bool isl = lane < C2;
    int cc = isl ? lane : lane - C2;
    const float4* wrow = (const float4*)&w2t[isl ? 0 : 1][cc][0];  // 528B row stride: 16B-aligned
    float a2 = 0.f;
    const float4* h4 = (const float4*)hsh[w];
#pragma unroll
    for (int k4 = 0; k4 < 32; k4++) {
      float4 hv = h4[k4];    // broadcast (same addr across lanes)
      float4 wv = wrow[k4];  // per-lane row, padded stride
      a2 = fmaf(hv.x, wv.x, a2);
      a2 = fmaf(hv.y, wv.y, a2);
      a2 = fmaf(hv.z, wv.z, a2);
      a2 = fmaf(hv.w, wv.w, a2);
    }
    float* Y = isl ? yl : yr;
    Y[(size_t)node * YPAD + cc] = a2;
  }
}

// ---------------- Layer-2 aggregation: 1 wave/node, 8-way edge-parallel, 2 ch/lane packed ----------------
// 8 lanes/edge (ch 2*(lane&7), 2*(lane&7)+1; lanes with ch>=10 idle), row8 DPP reduce,
// 8 edges in flight per wave -> per-node serial depth ~halved vs 16-lane groups.
__global__ __launch_bounds__(256) void k_agg2(const float* __restrict__ yl, const float* __restrict__ yr,
                                              const int* __restrict__ row_ptr, const int* __restrict__ colA,
                                              const float* __restrict__ att, const float* __restrict__ bias,
                                              float* __restrict__ outp) {
  int w = threadIdx.x >> 6;
  int node = blockIdx.x * 4 + w;
  if (node >= N_NODES) return;
  int lane = threadIdx.x & 63;
  int ch = 2 * (lane & 7);     // channel pair this lane owns
  int g  = lane >> 3;          // edge-group 0..7
  bool act = ch < C2;
  f32x2 xr = {0.f, 0.f};
  f32x2 a2 = {0.f, 0.f};
  if (act) {
    const float2* yr2 = (const float2*)(yr + (size_t)node * YPAD);
    float2 t = yr2[lane & 7];
    xr.x = t.x; xr.y = t.y;
    a2.x = att[ch] * LOG2E; a2.y = att[ch + 1] * LOG2E;
  }
  int beg = row_ptr[node], end = row_ptr[node + 1];
  float l = 0.f;
  f32x2 acc = {0.f, 0.f};
  const float2* ylL = (const float2*)yl + (lane & 7);   // row s at ((s<<4)>>1) float2 units

  auto update = [&](f32x2 xl) {
    f32x2 t = xl + xr;                       // v_pk_add_f32
    f32x2 u = t * NEG;                       // v_pk_mul_f32
    t = __builtin_elementwise_max(t, u);     // v_pk_max_f32
    f32x2 m = t * a2;                        // v_pk_mul_f32
    float p = row8_sum(m.x + m.y);           // 8-lane group reduce (inactive lanes add 0)
    float wgt = __builtin_amdgcn_exp2f(fminf(p, PCLAMP));
    l += wgt;
    acc += xl * wgt;                         // v_pk_fma_f32
  };
  auto load = [&](int s) -> f32x2 {
    f32x2 r = {0.f, 0.f};
    if (act) {
      float2 t = ylL[(size_t)s << 3];        // yl row stride 16 floats = 8 float2
      r.x = t.x; r.y = t.y;
    }
    return r;
  };

  int j = beg + g;
  for (; j + 8 < end; j += 16) {             // 2 edges of this group: j, j+8
    int s0 = colA[j], s1 = colA[j + 8];
    f32x2 x0 = load(s0), x1 = load(s1);
    update(x0); update(x1);
  }
  if (j < end) update(load(colA[j]));

  // fixed combine tree across the 8 groups (deterministic)
  for (int o = 8; o <= 32; o <<= 1) {
    l     += __shfl_xor(l, o);
    acc.x += __shfl_xor(acc.x, o);
    acc.y += __shfl_xor(acc.y, o);
  }
  if (g == 0 && act) {
    float2 o;
    o.x = acc.x / l + bias[ch];
    o.y = acc.y / l + bias[ch + 1];
    // rows are 40B; even-channel offsets are 8B-aligned
    *(float2*)(outp + (size_t)node * C2 + ch) = o;
  }
}

extern "C" void kernel_launch(void* const* d_in, const int* in_sizes, int n_in,
                              void* d_out, int out_size, void* d_ws, size_t ws_size,
                              hipStream_t stream) {
  const float* x    = (const float*)d_in[0];
  const int*   ei   = (const int*)d_in[1];
  const float* W1l  = (const float*)d_in[2];
  const float* W1r  = (const float*)d_in[3];
  const float* att1 = (const float*)d_in[4];
  const float* b1   = (const float*)d_in[5];
  const float* W2l  = (const float*)d_in[6];
  const float* W2r  = (const float*)d_in[7];
  const float* att2 = (const float*)d_in[8];
  const float* b2   = (const float*)d_in[9];
  float* out = (float*)d_out;

  char* ws = (char*)d_ws;
  size_t off = 0;
  auto take = [&](size_t bytes) -> char* {
    char* p = ws + off;
    off = (off + bytes + 511) & ~(size_t)511;
    return p;
  };
  unsigned short* Hlb = (unsigned short*)take((size_t)N_NODES * FDIM * sizeof(unsigned short)); // 25.6 MB
  unsigned short* Hrb = (unsigned short*)take((size_t)N_NODES * FDIM * sizeof(unsigned short)); // 25.6 MB
  unsigned short* Wt  = (unsigned short*)take((size_t)256 * 128 * sizeof(unsigned short));      // 64 KB
  float* yl      = (float*)take((size_t)N_NODES * YPAD * sizeof(float));   // 6.4 MB
  float* yr      = (float*)take((size_t)N_NODES * YPAD * sizeof(float));   // 6.4 MB
  int*   cnt     = (int*)take((size_t)N_NODES * sizeof(int));
  int*   row_ptr = (int*)take((size_t)(N_NODES + 1) * sizeof(int));
  int*   colA    = (int*)take((size_t)E_TOT * sizeof(int));
  int*   epos    = (int*)take((size_t)E_TOT * sizeof(int));
  int*   bsum    = (int*)take(256);
  if (off > ws_size) return;

  k_prep_w <<<NWT, 256, 0, stream>>>(W1l, W1r, Wt, cnt);
  k_gc     <<<GB1 + NDEG, 256, 0, stream>>>(x, Wt, Hlb, Hrb, ei, cnt, epos);
  k_scan1  <<<SCAN_NBLK, 256, 0, stream>>>(cnt, bsum);
  k_scan3  <<<SCAN_NBLK, 256, 0, stream>>>(cnt, bsum, row_ptr);
  k_scatter<<<(E_TOT + 255) / 256, 256, 0, stream>>>(ei, row_ptr, epos, colA);
  k_agg1   <<<(N_NODES + 3) / 4, 256, 0, stream>>>(Hlb, Hrb, row_ptr, colA, att1, b1, W2l, W2r, yl, yr);
  k_agg2   <<<(N_NODES + 3) / 4, 256, 0, stream>>>(yl, yr, row_ptr, colA, att2, b2, out);
}